// Round 9
// baseline (1117.099 us; speedup 1.0000x reference)
//
#include <hip/hip_runtime.h>

typedef unsigned short u16;
typedef unsigned int   u32;
typedef u16  u16x8 __attribute__((ext_vector_type(8)));
typedef u32  u32x4 __attribute__((ext_vector_type(4)));
typedef float f32x2 __attribute__((ext_vector_type(2)));
typedef float f32x4 __attribute__((ext_vector_type(4)));

#define DEVFN static __device__ __forceinline__

DEVFN float bf2f(u16 v) { u32 t = (u32)v << 16; return __builtin_bit_cast(float, t); }
DEVFN u16 f2bf(float f) {
  u32 u = __builtin_bit_cast(u32, f);
  return (u16)((u + 0x7fffu + ((u >> 16) & 1u)) >> 16);
}
DEVFN void unpk(u32 w, float& lo, float& hi) {
  lo = __builtin_bit_cast(float, w << 16);
  hi = __builtin_bit_cast(float, w & 0xffff0000u);
}

constexpr int Bb = 8, Tt = 16, Cc = 2048, Hh = 16, HD = 128, ML = 4096;
constexpr int N3 = 3 * Cc;
constexpr float SCALE = 0.08838834764831845f;
constexpr size_t NKV = (size_t)Bb * Hh * ML * HD;   // 67108864

// ws layout (f32 units) — 1,179,664 f32 = 4.72 MB (host-guarded)
constexpr size_t WS_FLAG = 0;        // int flags[16]
constexpr size_t WS_QKV  = 16;       // 128*6144 f32
constexpr size_t WS_QBF  = 786448;   // 128*2048 bf16 (u16) = 131072 f32
constexpr size_t WS_ATTN = 917520;   // 128*2048 f32
constexpr size_t WS_TOTAL = 1179664;

DEVFN int san_cl(int raw) {
  if (raw >= 0 && raw <= ML - Tt) return raw;
  float f = __builtin_bit_cast(float, raw);
  int v = (int)f;
  if (v >= 0 && v <= ML - Tt) return v;
  return 0;
}

// ---------------------------------------------------------------------------
// Per-input dtype probe (inputs may be bf16 or f32 on device; outputs are f32).
// bf16 words: bits[14:7] = exponent of low element, ~always in [100,140].
// f32 words: those bits are mantissa bits -> ~16% hit rate.
// ---------------------------------------------------------------------------
DEVFN int w9_probe1(const u32* p, long long base, long long stride, int lane) {
  u32 w = p[base + (long long)lane * stride];
  u32 e = (w >> 7) & 0xffu;
  unsigned long long b = __ballot(e >= 100u && e <= 140u);
  return (__popcll(b) >= 32) ? 0 : 1;   // 0 = bf16, 1 = f32
}

__global__ void w9_det(const u32* x, const u32* kb, const u32* vb,
                       const u32* wq, const u32* wo, const u32* ct,
                       const u32* st, int* flags)
{
  int lane = threadIdx.x;  // 64
  int f0 = w9_probe1(x,  40000,    997,    lane);
  int f1 = w9_probe1(kb, 10000000, 300001, lane);
  int f2 = w9_probe1(vb, 10000000, 300001, lane);
  int f3 = w9_probe1(wq, 2000000,  33331,  lane);
  int f4 = w9_probe1(wo, 700000,   17177,  lane);
  int f5 = w9_probe1(ct, 40000,    997,    lane);
  int f6 = w9_probe1(st, 40000,    997,    lane);
  if (lane == 0) {
    flags[0] = f0; flags[1] = f1; flags[2] = f2; flags[3] = f3;
    flags[4] = f4; flags[5] = f5; flags[6] = f6; flags[7] = 0;
  }
}

// ---------------------------------------------------------------------------
// GEMM [128 x 2048] @ [2048 x ldn] -> f32. m_tile 64, n_tile 32, KT 64.
// ia < 0 => A is f32 (ws). Output ALWAYS f32.
// ---------------------------------------------------------------------------
__global__ __launch_bounds__(256) void w9_mm(const void* __restrict__ A,
    const void* __restrict__ W, int ldn, float* __restrict__ outp,
    const int* __restrict__ flags, int ia, int iw)
{
  __shared__ float xs[64][66];
  __shared__ float wl[64][36];
  const int tid = threadIdx.x;
  const int n0 = blockIdx.x * 32, m0 = blockIdx.y * 64;
  const int ml = tid & 63, ng = tid >> 6;
  const int fa = (ia >= 0) ? flags[ia] : 1;
  const int fw = flags[iw];
  float acc[8] = {0.f,0.f,0.f,0.f,0.f,0.f,0.f,0.f};

  for (int k0 = 0; k0 < Cc; k0 += 64) {
    __syncthreads();
    if (fa) {
      for (int i = 0; i < 16; ++i) {
        int idx = i * 256 + tid, r = idx >> 6, c = idx & 63;
        xs[r][c] = ((const float*)A)[(size_t)(m0 + r) * Cc + k0 + c];
      }
    } else {
      for (int i = 0; i < 16; ++i) {
        int idx = i * 256 + tid, r = idx >> 6, c = idx & 63;
        xs[r][c] = bf2f(((const u16*)A)[(size_t)(m0 + r) * Cc + k0 + c]);
      }
    }
    if (fw) {
      for (int i = 0; i < 8; ++i) {
        int idx = i * 256 + tid, r = idx >> 5, c = idx & 31;
        wl[r][c] = ((const float*)W)[(size_t)(k0 + r) * ldn + n0 + c];
      }
    } else {
      for (int i = 0; i < 8; ++i) {
        int idx = i * 256 + tid, r = idx >> 5, c = idx & 31;
        wl[r][c] = bf2f(((const u16*)W)[(size_t)(k0 + r) * ldn + n0 + c]);
      }
    }
    __syncthreads();
#pragma unroll 8
    for (int kk = 0; kk < 64; kk += 2) {
      f32x2 xv = *(const f32x2*)&xs[ml][kk];
      f32x4 wa = *(const f32x4*)&wl[kk][ng * 8];
      f32x4 wb = *(const f32x4*)&wl[kk][ng * 8 + 4];
      f32x4 wc = *(const f32x4*)&wl[kk + 1][ng * 8];
      f32x4 wd = *(const f32x4*)&wl[kk + 1][ng * 8 + 4];
#pragma unroll
      for (int j = 0; j < 4; ++j) {
        acc[j]     += xv[0] * wa[j] + xv[1] * wc[j];
        acc[j + 4] += xv[0] * wb[j] + xv[1] * wd[j];
      }
    }
  }
  size_t ro = (size_t)(m0 + ml) * ldn + n0 + ng * 8;
  f32x4 a = {acc[0], acc[1], acc[2], acc[3]};
  f32x4 b = {acc[4], acc[5], acc[6], acc[7]};
  *(f32x4*)&outp[ro] = a;
  *(f32x4*)&outp[ro + 4] = b;
}

// ---------------------------------------------------------------------------
// RoPE q,k; scale q; q -> qbf (bf16, internal); fresh k,v -> F32 output cache.
// grid 128 (one per (b,t)), 256 thr.
// ---------------------------------------------------------------------------
__global__ __launch_bounds__(256) void w9_rot(const float* __restrict__ qkv,
    const void* __restrict__ ct, const void* __restrict__ st,
    const int* __restrict__ clp, u16* __restrict__ qbf,
    float* __restrict__ outk, float* __restrict__ outv,
    const int* __restrict__ flags)
{
  const int m = blockIdx.x, b = m >> 4, t = m & 15;
  const int cl = san_cl(*clp), pos = cl + t;
  const int fc = flags[5], fs = flags[6];
  const float* qr = qkv + (size_t)m * N3;
  for (int i0 = threadIdx.x; i0 < 1024; i0 += 256) {
    int h = i0 >> 6, i = i0 & 63;
    float cs = fc ? ((const float*)ct)[pos * 64 + i] : bf2f(((const u16*)ct)[pos * 64 + i]);
    float sn = fs ? ((const float*)st)[pos * 64 + i] : bf2f(((const u16*)st)[pos * 64 + i]);
    int col = h * HD + 2 * i;
    float q0 = qr[col], q1 = qr[col + 1];
    qbf[(size_t)m * Cc + col]     = f2bf((q0 * cs - q1 * sn) * SCALE);
    qbf[(size_t)m * Cc + col + 1] = f2bf((q1 * cs + q0 * sn) * SCALE);
    float k0 = qr[2048 + col], k1 = qr[2048 + col + 1];
    size_t ko = ((size_t)(b * Hh + h) * ML + pos) * HD + 2 * i;
    outk[ko]     = k0 * cs - k1 * sn;
    outk[ko + 1] = k1 * cs + k0 * sn;
    outv[ko]     = qr[4096 + col];
    outv[ko + 1] = qr[4096 + col + 1];
  }
}

// ---------------------------------------------------------------------------
// Cache copy (stale rows) -> F32 output cache. grid (128 bh, 64 rowblocks).
// ---------------------------------------------------------------------------
__global__ __launch_bounds__(256) void w9_cpy(const void* __restrict__ kin,
    const void* __restrict__ vin, const int* __restrict__ clp,
    float* __restrict__ outk, float* __restrict__ outv,
    const int* __restrict__ flags)
{
  const int tid = threadIdx.x;
  const int bh = blockIdx.x;
  const int r0 = blockIdx.y * 64;
  const int cl = san_cl(*clp), nl = cl + Tt;
  const int fk = flags[1], fv = flags[2];
  const size_t base = (size_t)bh * ML * HD;
  for (int ii = 0; ii < 4; ++ii) {
    int idx = ii * 256 + tid, r = idx >> 4, c8 = idx & 15;
    int jg = r0 + r;
    if (jg >= cl && jg < nl) continue;   // fresh rows: w9_rot wrote them
    size_t off = base + (size_t)jg * HD + c8 * 8;
    f32x4 ka, kb, va, vb;
    if (fk) {
      ka = *(const f32x4*)((const float*)kin + off);
      kb = *(const f32x4*)((const float*)kin + off + 4);
    } else {
      u16x8 kv = *(const u16x8*)((const u16*)kin + off);
      for (int u = 0; u < 4; ++u) { ka[u] = bf2f(kv[u]); kb[u] = bf2f(kv[u + 4]); }
    }
    if (fv) {
      va = *(const f32x4*)((const float*)vin + off);
      vb = *(const f32x4*)((const float*)vin + off + 4);
    } else {
      u16x8 vv = *(const u16x8*)((const u16*)vin + off);
      for (int u = 0; u < 4; ++u) { va[u] = bf2f(vv[u]); vb[u] = bf2f(vv[u + 4]); }
    }
    *(f32x4*)&outk[off] = ka;
    *(f32x4*)&outk[off + 4] = kb;
    *(f32x4*)&outv[off] = va;
    *(f32x4*)&outv[off + 4] = vb;
  }
}

// ---------------------------------------------------------------------------
// Flash attention over the F32 cache (staged to bf16 LDS internally).
// grid 128 (bh), 256 thr: t = tid>>4 (q row), js = tid&15.
// ---------------------------------------------------------------------------
__global__ __launch_bounds__(256) void w9_att(const u16* __restrict__ qbf,
    const float* __restrict__ kc, const float* __restrict__ vc,
    const int* __restrict__ clp, float* __restrict__ attn)
{
  __shared__ u32 kls[64][68];
  __shared__ u32 vls[64][68];
  __shared__ u32 qls[16][68];
  __shared__ float pls[16][68];

  const int tid = threadIdx.x;
  const int bh = blockIdx.x;
  const int cl = san_cl(*clp), nl = cl + Tt;
  const size_t base = (size_t)bh * ML * HD;
  const int b = bh >> 4, h = bh & 15;

  {
    const u16* qsrc = qbf + (size_t)b * Tt * Cc + h * HD;
    int r = tid >> 4, c8 = tid & 15;
    u16x8 qv = *(const u16x8*)&qsrc[(size_t)r * Cc + c8 * 8];
    *(u32x4*)&qls[r][c8 * 4] = __builtin_bit_cast(u32x4, qv);
  }

  const int t = tid >> 4;
  const int js = tid & 15;
  const int qpos = cl + t;
  float m_run = -1e30f, l_run = 0.f;
  float O[8] = {0.f,0.f,0.f,0.f,0.f,0.f,0.f,0.f};
  const int nt = (nl + 63) >> 6;

  for (int tile = 0; tile < nt; ++tile) {
    const int r0 = tile * 64;
    __syncthreads();
#pragma unroll
    for (int ii = 0; ii < 4; ++ii) {
      int idx = ii * 256 + tid, r = idx >> 4, c8 = idx & 15;
      size_t off = base + (size_t)(r0 + r) * HD + c8 * 8;
      f32x4 ka = *(const f32x4*)&kc[off];
      f32x4 kb = *(const f32x4*)&kc[off + 4];
      f32x4 va = *(const f32x4*)&vc[off];
      f32x4 vb = *(const f32x4*)&vc[off + 4];
      u16x8 kv, vv;
#pragma unroll
      for (int u = 0; u < 4; ++u) {
        kv[u] = f2bf(ka[u]); kv[u + 4] = f2bf(kb[u]);
        vv[u] = f2bf(va[u]); vv[u + 4] = f2bf(vb[u]);
      }
      *(u32x4*)&kls[r][c8 * 4] = __builtin_bit_cast(u32x4, kv);
      *(u32x4*)&vls[r][c8 * 4] = __builtin_bit_cast(u32x4, vv);
    }
    __syncthreads();

    float s[4] = {0.f,0.f,0.f,0.f};
#pragma unroll
    for (int dblk = 0; dblk < 4; ++dblk) {
      u32x4 qv[4];
#pragma unroll
      for (int g = 0; g < 4; ++g)
        qv[g] = *(const u32x4*)&qls[t][dblk * 16 + g * 4];
      float qf[32];
#pragma unroll
      for (int g = 0; g < 4; ++g)
#pragma unroll
        for (int u = 0; u < 4; ++u)
          unpk(qv[g][u], qf[g * 8 + 2 * u], qf[g * 8 + 2 * u + 1]);
#pragma unroll
      for (int jj = 0; jj < 4; ++jj) {
        const int j = js + jj * 16;
        u32x4 kv4[4];
#pragma unroll
        for (int g = 0; g < 4; ++g)
          kv4[g] = *(const u32x4*)&kls[j][dblk * 16 + g * 4];
        float a_ = s[jj];
#pragma unroll
        for (int g = 0; g < 4; ++g)
#pragma unroll
          for (int u = 0; u < 4; ++u) {
            float lo, hi; unpk(kv4[g][u], lo, hi);
            a_ += qf[g * 8 + 2 * u] * lo;
            a_ += qf[g * 8 + 2 * u + 1] * hi;
          }
        s[jj] = a_;
      }
    }

    float mt = -1e30f;
    bool val[4];
#pragma unroll
    for (int jj = 0; jj < 4; ++jj) {
      int jg = r0 + js + jj * 16;
      val[jj] = (jg <= qpos);
      if (!val[jj]) s[jj] = -1e30f;
      mt = fmaxf(mt, s[jj]);
    }
#pragma unroll
    for (int w = 1; w < 16; w <<= 1)
      mt = fmaxf(mt, __shfl_xor(mt, w));
    float mn = fmaxf(m_run, mt);
    float crr = __expf(m_run - mn);
    float p[4], ps = 0.f;
#pragma unroll
    for (int jj = 0; jj < 4; ++jj) {
      p[jj] = val[jj] ? __expf(s[jj] - mn) : 0.f;
      ps += p[jj];
    }
#pragma unroll
    for (int w = 1; w < 16; w <<= 1)
      ps += __shfl_xor(ps, w);
    l_run = l_run * crr + ps;
    m_run = mn;
#pragma unroll
    for (int jj = 0; jj < 4; ++jj)
      pls[t][js + jj * 16] = p[jj];
#pragma unroll
    for (int e = 0; e < 8; ++e) O[e] *= crr;
    __syncthreads();

    const int jmax = (nl - r0 < 64) ? (nl - r0) : 64;
#pragma unroll 2
    for (int j = 0; j < jmax; ++j) {
      float pv = pls[t][j];
      u32x4 vw = *(const u32x4*)&vls[j][js * 4];
#pragma unroll
      for (int g = 0; g < 4; ++g) {
        float lo, hi; unpk(vw[g], lo, hi);
        O[2 * g]     += pv * lo;
        O[2 * g + 1] += pv * hi;
      }
    }
  }

  const float inv = 1.0f / l_run;
  size_t ro = (size_t)(b * Tt + t) * Cc + h * HD + js * 8;
  f32x4 a = {O[0] * inv, O[1] * inv, O[2] * inv, O[3] * inv};
  f32x4 bb = {O[4] * inv, O[5] * inv, O[6] * inv, O[7] * inv};
  *(f32x4*)&attn[ro] = a;
  *(f32x4*)&attn[ro + 4] = bb;
}

// ---------------------------------------------------------------------------
extern "C" void kernel_launch(void* const* d_in, const int* in_sizes, int n_in,
                              void* d_out, int out_size, void* d_ws, size_t ws_size,
                              hipStream_t stream)
{
  const void* x    = d_in[0];
  const void* kin  = d_in[1];
  const void* vin  = d_in[2];
  const void* wqkv = d_in[3];
  const void* wout = d_in[4];
  const void* ct   = d_in[5];
  const void* st   = d_in[6];
  const int*  clp  = (const int*)d_in[7];

  // OUTPUTS ARE FLOAT32: (out[262144], k_buf[67108864], v_buf[67108864])
  float* out_f = (float*)d_out;
  float* outk  = out_f + (size_t)Bb * Tt * Cc;
  float* outv  = outk + NKV;
  float* ws = (float*)d_ws;

  if (ws_size < WS_TOTAL * sizeof(float)) return;   // guard (should not trigger)

  int* flags = (int*)(ws + WS_FLAG);
  u16* qbf   = (u16*)(ws + WS_QBF);

  w9_det<<<1, 64, 0, stream>>>((const u32*)x, (const u32*)kin, (const u32*)vin,
                               (const u32*)wqkv, (const u32*)wout,
                               (const u32*)ct, (const u32*)st, flags);
  w9_mm<<<dim3(N3 / 32, 2), 256, 0, stream>>>(x, wqkv, N3, ws + WS_QKV,
                                              flags, 0, 3);
  w9_rot<<<128, 256, 0, stream>>>(ws + WS_QKV, ct, st, clp, qbf, outk, outv, flags);
  w9_cpy<<<dim3(128, ML / 64), 256, 0, stream>>>(kin, vin, clp, outk, outv, flags);
  w9_att<<<128, 256, 0, stream>>>(qbf, outk, outv, clp, ws + WS_ATTN);
  w9_mm<<<dim3(Cc / 32, 2), 256, 0, stream>>>(ws + WS_ATTN, wout, Cc, out_f,
                                              flags, -1, 4);
}

// Round 10
// 489.551 us; speedup vs baseline: 2.2819x; 2.2819x over previous
//
#include <hip/hip_runtime.h>

typedef unsigned short u16;
typedef unsigned int   u32;
typedef u16  u16x8 __attribute__((ext_vector_type(8)));
typedef u32  u32x4 __attribute__((ext_vector_type(4)));
typedef float f32x2 __attribute__((ext_vector_type(2)));
typedef float f32x4 __attribute__((ext_vector_type(4)));

#define DEVFN static __device__ __forceinline__

DEVFN float bf2f(u16 v) { u32 t = (u32)v << 16; return __builtin_bit_cast(float, t); }
DEVFN u16 f2bf(float f) {
  u32 u = __builtin_bit_cast(u32, f);
  return (u16)((u + 0x7fffu + ((u >> 16) & 1u)) >> 16);
}
DEVFN void unpk(u32 w, float& lo, float& hi) {
  lo = __builtin_bit_cast(float, w << 16);
  hi = __builtin_bit_cast(float, w & 0xffff0000u);
}

constexpr int Bb = 8, Tt = 16, Cc = 2048, Hh = 16, HD = 128, ML = 4096;
constexpr int N3 = 3 * Cc;
constexpr float SCALE = 0.08838834764831845f;
constexpr size_t NKV = (size_t)Bb * Hh * ML * HD;   // 67108864
constexpr int NCH = 4;                              // attention K-split chunks

// ws layout (f32 units) — 4.72 MB guaranteed (same guard as round 9)
// [16, 786448) is TIME-MULTIPLEXED: qkv (mm1..rot) then attention partials.
constexpr size_t WS_FLAG = 0;
constexpr size_t WS_QKV  = 16;       // 786432 f32
constexpr size_t WS_PART = 16;       // 512 slots x 1056 f32 = 540672 (after rot)
constexpr size_t WS_QBF  = 786448;   // 131072 f32 (u16 q, scaled+roped)
constexpr size_t WS_ATTN = 917520;   // 262144 f32
constexpr size_t WS_TOTAL = 1179664;
constexpr int SLOT = 1056;           // u16 O[2048] (=1024 f32) + f32 m[16] + f32 l[16]

DEVFN int san_cl(int raw) {
  if (raw >= 0 && raw <= ML - Tt) return raw;
  float f = __builtin_bit_cast(float, raw);
  int v = (int)f;
  if (v >= 0 && v <= ML - Tt) return v;
  return 0;
}

// ---------------------------------------------------------------------------
DEVFN int w10_probe1(const u32* p, long long base, long long stride, int lane) {
  u32 w = p[base + (long long)lane * stride];
  u32 e = (w >> 7) & 0xffu;
  unsigned long long b = __ballot(e >= 100u && e <= 140u);
  return (__popcll(b) >= 32) ? 0 : 1;   // 0 = bf16, 1 = f32
}

__global__ void w10_det(const u32* x, const u32* kb, const u32* vb,
                        const u32* wq, const u32* wo, const u32* ct,
                        const u32* st, int* flags)
{
  int lane = threadIdx.x;  // 64
  int f0 = w10_probe1(x,  40000,    997,    lane);
  int f1 = w10_probe1(kb, 10000000, 300001, lane);
  int f2 = w10_probe1(vb, 10000000, 300001, lane);
  int f3 = w10_probe1(wq, 2000000,  33331,  lane);
  int f4 = w10_probe1(wo, 700000,   17177,  lane);
  int f5 = w10_probe1(ct, 40000,    997,    lane);
  int f6 = w10_probe1(st, 40000,    997,    lane);
  if (lane == 0) {
    flags[0] = f0; flags[1] = f1; flags[2] = f2; flags[3] = f3;
    flags[4] = f4; flags[5] = f5; flags[6] = f6; flags[7] = 0;
  }
}

// ---------------------------------------------------------------------------
// GEMM core: 64(M) x 32(N) tile over K range [kbeg, kbeg+256). acc[8]/thread.
// ---------------------------------------------------------------------------
DEVFN void w10_gemm_core(const void* __restrict__ A, const void* __restrict__ W,
                         int ldn, int fa, int fw, int kbeg, int m0, int n0,
                         float (&xs)[64][66], float (&wl)[64][36], float (&acc)[8])
{
  const int tid = threadIdx.x;
  const int ml = tid & 63, ng = tid >> 6;
  for (int k0 = kbeg; k0 < kbeg + 256; k0 += 64) {
    __syncthreads();
    if (fa) {
      for (int i = 0; i < 16; ++i) {
        int idx = i * 256 + tid, r = idx >> 6, c = idx & 63;
        xs[r][c] = ((const float*)A)[(size_t)(m0 + r) * Cc + k0 + c];
      }
    } else {
      for (int i = 0; i < 16; ++i) {
        int idx = i * 256 + tid, r = idx >> 6, c = idx & 63;
        xs[r][c] = bf2f(((const u16*)A)[(size_t)(m0 + r) * Cc + k0 + c]);
      }
    }
    if (fw) {
      for (int i = 0; i < 8; ++i) {
        int idx = i * 256 + tid, r = idx >> 5, c = idx & 31;
        wl[r][c] = ((const float*)W)[(size_t)(k0 + r) * ldn + n0 + c];
      }
    } else {
      for (int i = 0; i < 8; ++i) {
        int idx = i * 256 + tid, r = idx >> 5, c = idx & 31;
        wl[r][c] = bf2f(((const u16*)W)[(size_t)(k0 + r) * ldn + n0 + c]);
      }
    }
    __syncthreads();
#pragma unroll 8
    for (int kk = 0; kk < 64; kk += 2) {
      f32x2 xv = *(const f32x2*)&xs[ml][kk];
      f32x4 wa = *(const f32x4*)&wl[kk][ng * 8];
      f32x4 wb = *(const f32x4*)&wl[kk][ng * 8 + 4];
      f32x4 wc = *(const f32x4*)&wl[kk + 1][ng * 8];
      f32x4 wd = *(const f32x4*)&wl[kk + 1][ng * 8 + 4];
#pragma unroll
      for (int j = 0; j < 4; ++j) {
        acc[j]     += xv[0] * wa[j] + xv[1] * wc[j];
        acc[j + 4] += xv[0] * wb[j] + xv[1] * wd[j];
      }
    }
  }
}

// GEMM1: k-split partials. grid (ldn/32, 2, 8). partials: part[s*128*ldn + ...]
__global__ __launch_bounds__(256) void w10_mm1(const void* __restrict__ A,
    const void* __restrict__ W, int ldn, float* __restrict__ part,
    const int* __restrict__ flags)
{
  __shared__ float xs[64][66];
  __shared__ float wl[64][36];
  const int n0 = blockIdx.x * 32, m0 = blockIdx.y * 64, s = blockIdx.z;
  const int fa = flags[0], fw = flags[3];
  float acc[8] = {0.f,0.f,0.f,0.f,0.f,0.f,0.f,0.f};
  w10_gemm_core(A, W, ldn, fa, fw, s * 256, m0, n0, xs, wl, acc);
  const int ml = threadIdx.x & 63, ng = threadIdx.x >> 6;
  size_t ro = (size_t)s * 128 * ldn + (size_t)(m0 + ml) * ldn + n0 + ng * 8;
  f32x4 a = {acc[0], acc[1], acc[2], acc[3]};
  f32x4 b = {acc[4], acc[5], acc[6], acc[7]};
  *(f32x4*)&part[ro] = a;
  *(f32x4*)&part[ro + 4] = b;
}

// reduce 8 partials -> qkv. grid 768 x 256 (f32x4 per thread)
__global__ __launch_bounds__(256) void w10_red1(const float* __restrict__ part,
                                                float* __restrict__ qkv)
{
  size_t e4 = (size_t)blockIdx.x * 256 + threadIdx.x;
  f32x4 acc = {0.f, 0.f, 0.f, 0.f};
#pragma unroll
  for (int s = 0; s < 8; ++s) {
    f32x4 v = *(const f32x4*)&part[(size_t)s * 786432 + e4 * 4];
    acc[0] += v[0]; acc[1] += v[1]; acc[2] += v[2]; acc[3] += v[3];
  }
  *(f32x4*)&qkv[e4 * 4] = acc;
}

// GEMM2: k-split + atomic accumulate into pre-zeroed out. grid (64, 2, 8)
__global__ __launch_bounds__(256) void w10_mm2a(const float* __restrict__ A,
    const void* __restrict__ W, int ldn, float* __restrict__ outp,
    const int* __restrict__ flags)
{
  __shared__ float xs[64][66];
  __shared__ float wl[64][36];
  const int n0 = blockIdx.x * 32, m0 = blockIdx.y * 64, s = blockIdx.z;
  const int fw = flags[4];
  float acc[8] = {0.f,0.f,0.f,0.f,0.f,0.f,0.f,0.f};
  w10_gemm_core(A, W, ldn, 1, fw, s * 256, m0, n0, xs, wl, acc);
  const int ml = threadIdx.x & 63, ng = threadIdx.x >> 6;
  size_t ro = (size_t)(m0 + ml) * ldn + n0 + ng * 8;
#pragma unroll
  for (int j = 0; j < 8; ++j) atomicAdd(&outp[ro + j], acc[j]);
}

__global__ __launch_bounds__(256) void w10_zero(float* __restrict__ outp) {
  size_t i = ((size_t)blockIdx.x * 256 + threadIdx.x) * 4;
  f32x4 z = {0.f, 0.f, 0.f, 0.f};
  *(f32x4*)&outp[i] = z;
}

// ---------------------------------------------------------------------------
// RoPE q,k; scale q; q -> qbf (bf16); fresh k,v -> F32 output cache.
// ---------------------------------------------------------------------------
__global__ __launch_bounds__(256) void w10_rot(const float* __restrict__ qkv,
    const void* __restrict__ ct, const void* __restrict__ st,
    const int* __restrict__ clp, u16* __restrict__ qbf,
    float* __restrict__ outk, float* __restrict__ outv,
    const int* __restrict__ flags)
{
  const int m = blockIdx.x, b = m >> 4, t = m & 15;
  const int cl = san_cl(*clp), pos = cl + t;
  const int fc = flags[5], fs = flags[6];
  const float* qr = qkv + (size_t)m * N3;
  for (int i0 = threadIdx.x; i0 < 1024; i0 += 256) {
    int h = i0 >> 6, i = i0 & 63;
    float cs = fc ? ((const float*)ct)[pos * 64 + i] : bf2f(((const u16*)ct)[pos * 64 + i]);
    float sn = fs ? ((const float*)st)[pos * 64 + i] : bf2f(((const u16*)st)[pos * 64 + i]);
    int col = h * HD + 2 * i;
    float q0 = qr[col], q1 = qr[col + 1];
    qbf[(size_t)m * Cc + col]     = f2bf((q0 * cs - q1 * sn) * SCALE);
    qbf[(size_t)m * Cc + col + 1] = f2bf((q1 * cs + q0 * sn) * SCALE);
    float k0 = qr[2048 + col], k1 = qr[2048 + col + 1];
    size_t ko = ((size_t)(b * Hh + h) * ML + pos) * HD + 2 * i;
    outk[ko]     = k0 * cs - k1 * sn;
    outk[ko + 1] = k1 * cs + k0 * sn;
    outv[ko]     = qr[4096 + col];
    outv[ko + 1] = qr[4096 + col + 1];
  }
}

// ---------------------------------------------------------------------------
// FUSED cache-copy + flash-attention partials.
// grid (NCH=4 chunks, 128 bh), 256 thr. Chunk c handles subtiles c, c+4, ...
// of 64 rows each (64 subtiles = full 4096-row copy; attention only < nl).
// Partials: O bf16[2048] + m,l f32[16] per (bh,chunk) slot in ws.
// ---------------------------------------------------------------------------
__global__ __launch_bounds__(256) void w10_attc(
    const void* __restrict__ kin, const void* __restrict__ vin,
    const u16* __restrict__ qbf, const int* __restrict__ clp,
    float* __restrict__ outk, float* __restrict__ outv,
    float* __restrict__ part, const int* __restrict__ flags)
{
  __shared__ u32 kls[64][68];
  __shared__ u32 vls[64][68];
  __shared__ u32 qls[16][68];
  __shared__ float pls[16][68];

  const int tid = threadIdx.x;
  const int chunk = blockIdx.x;   // 0..3
  const int bh = blockIdx.y;      // 0..127
  const int cl = san_cl(*clp), nl = cl + Tt;
  const int fk = flags[1], fv = flags[2];
  const size_t base = (size_t)bh * ML * HD;
  const int b = bh >> 4, h = bh & 15;

  { // stage q tile (16 x 128 bf16)
    const u16* qsrc = qbf + (size_t)b * Tt * Cc + h * HD;
    int r = tid >> 4, c8 = tid & 15;
    u16x8 qv = *(const u16x8*)&qsrc[(size_t)r * Cc + c8 * 8];
    *(u32x4*)&qls[r][c8 * 4] = __builtin_bit_cast(u32x4, qv);
  }

  const int t = tid >> 4;
  const int js = tid & 15;
  const int qpos = cl + t;
  float m_run = -1e30f, l_run = 0.f;
  float O[8] = {0.f,0.f,0.f,0.f,0.f,0.f,0.f,0.f};

  for (int st8 = chunk; st8 < 64; st8 += NCH) {
    const int r0 = st8 * 64;
    __syncthreads();
    // stage 64 K + 64 V rows to LDS (bf16) while copying f32 -> output cache
#pragma unroll
    for (int ii = 0; ii < 4; ++ii) {
      int idx = ii * 256 + tid, r = idx >> 4, c8 = idx & 15;
      int jg = r0 + r;
      size_t off = base + (size_t)jg * HD + c8 * 8;
      bool fresh = (jg >= cl) && (jg < nl);
      f32x4 ka, kb, va, vb;
      if (fresh) {               // rot already wrote these rows (f32)
        ka = *(const f32x4*)&outk[off];
        kb = *(const f32x4*)&outk[off + 4];
        va = *(const f32x4*)&outv[off];
        vb = *(const f32x4*)&outv[off + 4];
      } else {
        if (fk) {
          ka = *(const f32x4*)((const float*)kin + off);
          kb = *(const f32x4*)((const float*)kin + off + 4);
        } else {
          u16x8 kv8 = *(const u16x8*)((const u16*)kin + off);
          for (int u = 0; u < 4; ++u) { ka[u] = bf2f(kv8[u]); kb[u] = bf2f(kv8[u + 4]); }
        }
        if (fv) {
          va = *(const f32x4*)((const float*)vin + off);
          vb = *(const f32x4*)((const float*)vin + off + 4);
        } else {
          u16x8 vv8 = *(const u16x8*)((const u16*)vin + off);
          for (int u = 0; u < 4; ++u) { va[u] = bf2f(vv8[u]); vb[u] = bf2f(vv8[u + 4]); }
        }
        *(f32x4*)&outk[off] = ka;
        *(f32x4*)&outk[off + 4] = kb;
        *(f32x4*)&outv[off] = va;
        *(f32x4*)&outv[off + 4] = vb;
      }
      u16x8 kv, vv;
#pragma unroll
      for (int u = 0; u < 4; ++u) {
        kv[u] = f2bf(ka[u]); kv[u + 4] = f2bf(kb[u]);
        vv[u] = f2bf(va[u]); vv[u + 4] = f2bf(vb[u]);
      }
      *(u32x4*)&kls[r][c8 * 4] = __builtin_bit_cast(u32x4, kv);
      *(u32x4*)&vls[r][c8 * 4] = __builtin_bit_cast(u32x4, vv);
    }
    __syncthreads();
    if (r0 >= nl) continue;   // copy-only subtile (uniform branch)

    // ---- S = q_t . k_j for this thread's 4 j's
    float s[4] = {0.f,0.f,0.f,0.f};
#pragma unroll
    for (int dblk = 0; dblk < 4; ++dblk) {
      u32x4 qv[4];
#pragma unroll
      for (int g = 0; g < 4; ++g)
        qv[g] = *(const u32x4*)&qls[t][dblk * 16 + g * 4];
      float qf[32];
#pragma unroll
      for (int g = 0; g < 4; ++g)
#pragma unroll
        for (int u = 0; u < 4; ++u)
          unpk(qv[g][u], qf[g * 8 + 2 * u], qf[g * 8 + 2 * u + 1]);
#pragma unroll
      for (int jj = 0; jj < 4; ++jj) {
        const int j = js + jj * 16;
        u32x4 kv4[4];
#pragma unroll
        for (int g = 0; g < 4; ++g)
          kv4[g] = *(const u32x4*)&kls[j][dblk * 16 + g * 4];
        float a_ = s[jj];
#pragma unroll
        for (int g = 0; g < 4; ++g)
#pragma unroll
          for (int u = 0; u < 4; ++u) {
            float lo, hi; unpk(kv4[g][u], lo, hi);
            a_ += qf[g * 8 + 2 * u] * lo;
            a_ += qf[g * 8 + 2 * u + 1] * hi;
          }
        s[jj] = a_;
      }
    }

    // ---- mask + online softmax over the 16-lane group (one t-row)
    float mt = -1e30f;
    bool val[4];
#pragma unroll
    for (int jj = 0; jj < 4; ++jj) {
      int jg = r0 + js + jj * 16;
      val[jj] = (jg <= qpos);
      if (!val[jj]) s[jj] = -1e30f;
      mt = fmaxf(mt, s[jj]);
    }
#pragma unroll
    for (int w = 1; w < 16; w <<= 1)
      mt = fmaxf(mt, __shfl_xor(mt, w));
    float mn = fmaxf(m_run, mt);
    float crr = __expf(m_run - mn);
    float p[4], ps = 0.f;
#pragma unroll
    for (int jj = 0; jj < 4; ++jj) {
      p[jj] = val[jj] ? __expf(s[jj] - mn) : 0.f;
      ps += p[jj];
    }
#pragma unroll
    for (int w = 1; w < 16; w <<= 1)
      ps += __shfl_xor(ps, w);
    l_run = l_run * crr + ps;
    m_run = mn;
#pragma unroll
    for (int jj = 0; jj < 4; ++jj)
      pls[t][js + jj * 16] = p[jj];
#pragma unroll
    for (int e = 0; e < 8; ++e) O[e] *= crr;
    __syncthreads();

    // ---- PV
    const int jmax = (nl - r0 < 64) ? (nl - r0) : 64;
#pragma unroll 2
    for (int j = 0; j < jmax; ++j) {
      float pv = pls[t][j];
      u32x4 vw = *(const u32x4*)&vls[j][js * 4];
#pragma unroll
      for (int g = 0; g < 4; ++g) {
        float lo, hi; unpk(vw[g], lo, hi);
        O[2 * g]     += pv * lo;
        O[2 * g + 1] += pv * hi;
      }
    }
  }

  // ---- write partial slot: O (bf16) + m,l (f32)
  float* sb = part + (size_t)(bh * NCH + chunk) * SLOT;
  u16* ob = (u16*)sb;
  u16x8 ov;
#pragma unroll
  for (int e = 0; e < 8; ++e) ov[e] = f2bf(O[e]);
  *(u16x8*)&ob[t * HD + js * 8] = ov;
  if (js == 0) { sb[1024 + t] = m_run; sb[1040 + t] = l_run; }
}

// ---------------------------------------------------------------------------
// Combine NCH chunk partials -> attn (f32). grid 2048 (bh*16+t), 128 thr (d).
// ---------------------------------------------------------------------------
__global__ __launch_bounds__(128) void w10_comb(const float* __restrict__ part,
                                                float* __restrict__ attn)
{
  const int row = blockIdx.x;
  const int d = threadIdx.x;
  const int bh = row >> 4, t = row & 15;
  const float* pb = part + (size_t)bh * NCH * SLOT;
  float M = -1e30f;
#pragma unroll
  for (int c = 0; c < NCH; ++c) M = fmaxf(M, pb[c * SLOT + 1024 + t]);
  float L = 0.f, acc = 0.f;
#pragma unroll
  for (int c = 0; c < NCH; ++c) {
    float w = __expf(pb[c * SLOT + 1024 + t] - M);
    L   += w * pb[c * SLOT + 1040 + t];
    acc += w * bf2f(((const u16*)(pb + c * SLOT))[t * HD + d]);
  }
  const int b = bh >> 4, h = bh & 15;
  attn[(size_t)(b * Tt + t) * Cc + h * HD + d] = acc / L;
}

// ---------------------------------------------------------------------------
extern "C" void kernel_launch(void* const* d_in, const int* in_sizes, int n_in,
                              void* d_out, int out_size, void* d_ws, size_t ws_size,
                              hipStream_t stream)
{
  const void* x    = d_in[0];
  const void* kin  = d_in[1];
  const void* vin  = d_in[2];
  const void* wqkv = d_in[3];
  const void* wout = d_in[4];
  const void* ct   = d_in[5];
  const void* st   = d_in[6];
  const int*  clp  = (const int*)d_in[7];

  // outputs are f32: (out[262144], k_buf[67108864], v_buf[67108864])
  float* out_f = (float*)d_out;
  float* outk  = out_f + (size_t)Bb * Tt * Cc;
  float* outv  = outk + NKV;
  float* ws = (float*)d_ws;

  if (ws_size < WS_TOTAL * sizeof(float)) return;

  int* flags = (int*)(ws + WS_FLAG);
  u16* qbf   = (u16*)(ws + WS_QBF);

  w10_det<<<1, 64, 0, stream>>>((const u32*)x, (const u32*)kin, (const u32*)vin,
                                (const u32*)wqkv, (const u32*)wout,
                                (const u32*)ct, (const u32*)st, flags);
  // GEMM1 k-split: partials parked in outv (dead until rot/attc rewrite it)
  w10_mm1<<<dim3(N3 / 32, 2, 8), 256, 0, stream>>>(x, wqkv, N3, outv, flags);
  w10_red1<<<768, 256, 0, stream>>>(outv, ws + WS_QKV);
  w10_rot<<<128, 256, 0, stream>>>(ws + WS_QKV, ct, st, clp, qbf, outk, outv, flags);
  // fused copy + attention partials (partials reuse the now-dead qkv region)
  w10_attc<<<dim3(NCH, 128), 256, 0, stream>>>(kin, vin, qbf, clp,
                                               outk, outv, ws + WS_PART, flags);
  w10_comb<<<2048, 128, 0, stream>>>(ws + WS_PART, ws + WS_ATTN);
  // GEMM2 k-split with atomic accumulate into pre-zeroed out
  w10_zero<<<256, 256, 0, stream>>>(out_f);
  w10_mm2a<<<dim3(Cc / 32, 2, 8), 256, 0, stream>>>(ws + WS_ATTN, wout, Cc,
                                                    out_f, flags);
}

// Round 11
// 442.372 us; speedup vs baseline: 2.5252x; 1.1066x over previous
//
#include <hip/hip_runtime.h>

typedef unsigned short u16;
typedef unsigned int   u32;
typedef u16  u16x4 __attribute__((ext_vector_type(4)));
typedef u16  u16x8 __attribute__((ext_vector_type(8)));
typedef u32  u32x4 __attribute__((ext_vector_type(4)));
typedef short s16x8 __attribute__((ext_vector_type(8)));
typedef float f32x2 __attribute__((ext_vector_type(2)));
typedef float f32x4 __attribute__((ext_vector_type(4)));

#define DEVFN static __device__ __forceinline__

DEVFN float bf2f(u16 v) { u32 t = (u32)v << 16; return __builtin_bit_cast(float, t); }
DEVFN u16 f2bf(float f) {
  u32 u = __builtin_bit_cast(u32, f);
  return (u16)((u + 0x7fffu + ((u >> 16) & 1u)) >> 16);
}
DEVFN void unpk(u32 w, float& lo, float& hi) {
  lo = __builtin_bit_cast(float, w << 16);
  hi = __builtin_bit_cast(float, w & 0xffff0000u);
}

constexpr int Bb = 8, Tt = 16, Cc = 2048, Hh = 16, HD = 128, ML = 4096;
constexpr int N3 = 3 * Cc;
constexpr float SCALE = 0.08838834764831845f;
constexpr size_t NKV = (size_t)Bb * Hh * ML * HD;   // 67108864
constexpr int NCH = 4;                              // attention K-split chunks

// ws layout (f32 units) — 4.72 MB guaranteed
// [16, 786448) time-multiplexed: qkv (mm1..rot) then attention partials.
constexpr size_t WS_FLAG = 0;
constexpr size_t WS_QKV  = 16;       // 786432 f32
constexpr size_t WS_PART = 16;       // 512 slots x 1056 f32 (after rot)
constexpr size_t WS_QBF  = 786448;   // 131072 f32 (u16 q, scaled+roped)
constexpr size_t WS_ATTN = 917520;   // 262144 f32
constexpr size_t WS_TOTAL = 1179664;
constexpr int SLOT = 1056;           // u16 O[2048] + f32 m[16] + f32 l[16]

DEVFN int san_cl(int raw) {
  if (raw >= 0 && raw <= ML - Tt) return raw;
  float f = __builtin_bit_cast(float, raw);
  int v = (int)f;
  if (v >= 0 && v <= ML - Tt) return v;
  return 0;
}

// ---------------------------------------------------------------------------
DEVFN int w11_probe1(const u32* p, long long base, long long stride, int lane) {
  u32 w = p[base + (long long)lane * stride];
  u32 e = (w >> 7) & 0xffu;
  unsigned long long b = __ballot(e >= 100u && e <= 140u);
  return (__popcll(b) >= 32) ? 0 : 1;   // 0 = bf16, 1 = f32
}

__global__ void w11_det(const u32* x, const u32* kb, const u32* vb,
                        const u32* wq, const u32* wo, const u32* ct,
                        const u32* st, int* flags)
{
  int lane = threadIdx.x;  // 64
  int f0 = w11_probe1(x,  40000,    997,    lane);
  int f1 = w11_probe1(kb, 10000000, 300001, lane);
  int f2 = w11_probe1(vb, 10000000, 300001, lane);
  int f3 = w11_probe1(wq, 2000000,  33331,  lane);
  int f4 = w11_probe1(wo, 700000,   17177,  lane);
  int f5 = w11_probe1(ct, 40000,    997,    lane);
  int f6 = w11_probe1(st, 40000,    997,    lane);
  if (lane == 0) {
    flags[0] = f0; flags[1] = f1; flags[2] = f2; flags[3] = f3;
    flags[4] = f4; flags[5] = f5; flags[6] = f6; flags[7] = 0;
  }
}

// ---------------------------------------------------------------------------
// MFMA bf16 GEMM: [128 x 2048] @ [2048 x ldn] -> f32.
// Block 256 thr (4 waves), tile 64M x 64N, K-step 32, no K-split.
// mfma_f32_16x16x32_bf16 layout (verified m89/m91):
//   A-frag: lane l holds A[l&15][(l>>4)*8 + e]
//   B-frag: lane l holds B[(l>>4)*8 + e][l&15]
//   D:      row = (l>>4)*4 + j, col = l&15
// Bs staged pre-swizzled [kg][n][e] so both operand reads are ds_read_b128.
// ---------------------------------------------------------------------------
__global__ __launch_bounds__(256) void w11_mm(const void* __restrict__ A,
    const void* __restrict__ W, int ldn, float* __restrict__ outp,
    const int* __restrict__ flags, int ia, int iw)
{
  __shared__ u16 As[64][40];      // row stride 80 B (16B-aligned)
  __shared__ u16 Bs[4][66][8];    // kg stride 1056 B
  const int tid = threadIdx.x;
  const int n0 = blockIdx.x * 64, m0 = blockIdx.y * 64;
  const int fa = (ia >= 0) ? flags[ia] : 1;
  const int fw = flags[iw];
  const int l = tid & 63, wv = tid >> 6;
  f32x4 acc[4] = {{0.f,0.f,0.f,0.f},{0.f,0.f,0.f,0.f},
                  {0.f,0.f,0.f,0.f},{0.f,0.f,0.f,0.f}};

  const int ar = tid >> 2, ak = (tid & 3) * 8;   // A staging: row, k-off

  for (int k0 = 0; k0 < Cc; k0 += 32) {
    __syncthreads();
    // ---- stage A 64x32 -> As (bf16)
    if (fa) {
      const float* Af = (const float*)A + (size_t)(m0 + ar) * Cc + k0 + ak;
      f32x4 a0 = *(const f32x4*)Af;
      f32x4 a1 = *(const f32x4*)(Af + 4);
      u16x8 av;
#pragma unroll
      for (int u = 0; u < 4; ++u) { av[u] = f2bf(a0[u]); av[u + 4] = f2bf(a1[u]); }
      *(u16x8*)&As[ar][ak] = av;
    } else {
      u16x8 av = *(const u16x8*)((const u16*)A + (size_t)(m0 + ar) * Cc + k0 + ak);
      *(u16x8*)&As[ar][ak] = av;
    }
    // ---- stage B 32x64 -> Bs swizzled [kk>>3][n][kk&7]
#pragma unroll
    for (int i = 0; i < 2; ++i) {
      int kk = i * 16 + (tid >> 4);
      int nn = (tid & 15) * 4;
      if (fw) {
        f32x4 bv = *(const f32x4*)((const float*)W + (size_t)(k0 + kk) * ldn + n0 + nn);
#pragma unroll
        for (int u = 0; u < 4; ++u) Bs[kk >> 3][nn + u][kk & 7] = f2bf(bv[u]);
      } else {
        u16x4 bv = *(const u16x4*)((const u16*)W + (size_t)(k0 + kk) * ldn + n0 + nn);
#pragma unroll
        for (int u = 0; u < 4; ++u) Bs[kk >> 3][nn + u][kk & 7] = bv[u];
      }
    }
    __syncthreads();
    // ---- compute: 1 A-frag + 4 B-frags -> 4 MFMA
    s16x8 a = __builtin_bit_cast(s16x8,
        *(const u16x8*)&As[wv * 16 + (l & 15)][(l >> 4) * 8]);
#pragma unroll
    for (int nf = 0; nf < 4; ++nf) {
      s16x8 b = __builtin_bit_cast(s16x8,
          *(const u16x8*)&Bs[l >> 4][nf * 16 + (l & 15)][0]);
      acc[nf] = __builtin_amdgcn_mfma_f32_16x16x32_bf16(a, b, acc[nf], 0, 0, 0);
    }
  }
  // ---- epilogue: D[row=(l>>4)*4+j][col=l&15] per frag
  const int row = m0 + wv * 16 + (l >> 4) * 4;
  const int colb = n0 + (l & 15);
#pragma unroll
  for (int nf = 0; nf < 4; ++nf)
#pragma unroll
    for (int j = 0; j < 4; ++j)
      outp[(size_t)(row + j) * ldn + colb + nf * 16] = acc[nf][j];
}

// ---------------------------------------------------------------------------
// RoPE q,k; scale q; q -> qbf (bf16); fresh k,v -> F32 output cache.
// ---------------------------------------------------------------------------
__global__ __launch_bounds__(256) void w11_rot(const float* __restrict__ qkv,
    const void* __restrict__ ct, const void* __restrict__ st,
    const int* __restrict__ clp, u16* __restrict__ qbf,
    float* __restrict__ outk, float* __restrict__ outv,
    const int* __restrict__ flags)
{
  const int m = blockIdx.x, b = m >> 4, t = m & 15;
  const int cl = san_cl(*clp), pos = cl + t;
  const int fc = flags[5], fs = flags[6];
  const float* qr = qkv + (size_t)m * N3;
  for (int i0 = threadIdx.x; i0 < 1024; i0 += 256) {
    int h = i0 >> 6, i = i0 & 63;
    float cs = fc ? ((const float*)ct)[pos * 64 + i] : bf2f(((const u16*)ct)[pos * 64 + i]);
    float sn = fs ? ((const float*)st)[pos * 64 + i] : bf2f(((const u16*)st)[pos * 64 + i]);
    int col = h * HD + 2 * i;
    float q0 = qr[col], q1 = qr[col + 1];
    qbf[(size_t)m * Cc + col]     = f2bf((q0 * cs - q1 * sn) * SCALE);
    qbf[(size_t)m * Cc + col + 1] = f2bf((q1 * cs + q0 * sn) * SCALE);
    float k0 = qr[2048 + col], k1 = qr[2048 + col + 1];
    size_t ko = ((size_t)(b * Hh + h) * ML + pos) * HD + 2 * i;
    outk[ko]     = k0 * cs - k1 * sn;
    outk[ko + 1] = k1 * cs + k0 * sn;
    outv[ko]     = qr[4096 + col];
    outv[ko + 1] = qr[4096 + col + 1];
  }
}

// ---------------------------------------------------------------------------
// FUSED cache-copy + flash-attention partials (unchanged from round 10).
// grid (NCH=4, 128 bh), 256 thr. Chunk c handles subtiles c, c+4, ... (64 rows).
// ---------------------------------------------------------------------------
__global__ __launch_bounds__(256) void w11_attc(
    const void* __restrict__ kin, const void* __restrict__ vin,
    const u16* __restrict__ qbf, const int* __restrict__ clp,
    float* __restrict__ outk, float* __restrict__ outv,
    float* __restrict__ part, const int* __restrict__ flags)
{
  __shared__ u32 kls[64][68];
  __shared__ u32 vls[64][68];
  __shared__ u32 qls[16][68];
  __shared__ float pls[16][68];

  const int tid = threadIdx.x;
  const int chunk = blockIdx.x;   // 0..3
  const int bh = blockIdx.y;      // 0..127
  const int cl = san_cl(*clp), nl = cl + Tt;
  const int fk = flags[1], fv = flags[2];
  const size_t base = (size_t)bh * ML * HD;
  const int b = bh >> 4, h = bh & 15;

  { // stage q tile (16 x 128 bf16)
    const u16* qsrc = qbf + (size_t)b * Tt * Cc + h * HD;
    int r = tid >> 4, c8 = tid & 15;
    u16x8 qv = *(const u16x8*)&qsrc[(size_t)r * Cc + c8 * 8];
    *(u32x4*)&qls[r][c8 * 4] = __builtin_bit_cast(u32x4, qv);
  }

  const int t = tid >> 4;
  const int js = tid & 15;
  const int qpos = cl + t;
  float m_run = -1e30f, l_run = 0.f;
  float O[8] = {0.f,0.f,0.f,0.f,0.f,0.f,0.f,0.f};

  for (int st8 = chunk; st8 < 64; st8 += NCH) {
    const int r0 = st8 * 64;
    __syncthreads();
#pragma unroll
    for (int ii = 0; ii < 4; ++ii) {
      int idx = ii * 256 + tid, r = idx >> 4, c8 = idx & 15;
      int jg = r0 + r;
      size_t off = base + (size_t)jg * HD + c8 * 8;
      bool fresh = (jg >= cl) && (jg < nl);
      f32x4 ka, kb, va, vb;
      if (fresh) {
        ka = *(const f32x4*)&outk[off];
        kb = *(const f32x4*)&outk[off + 4];
        va = *(const f32x4*)&outv[off];
        vb = *(const f32x4*)&outv[off + 4];
      } else {
        if (fk) {
          ka = *(const f32x4*)((const float*)kin + off);
          kb = *(const f32x4*)((const float*)kin + off + 4);
        } else {
          u16x8 kv8 = *(const u16x8*)((const u16*)kin + off);
          for (int u = 0; u < 4; ++u) { ka[u] = bf2f(kv8[u]); kb[u] = bf2f(kv8[u + 4]); }
        }
        if (fv) {
          va = *(const f32x4*)((const float*)vin + off);
          vb = *(const f32x4*)((const float*)vin + off + 4);
        } else {
          u16x8 vv8 = *(const u16x8*)((const u16*)vin + off);
          for (int u = 0; u < 4; ++u) { va[u] = bf2f(vv8[u]); vb[u] = bf2f(vv8[u + 4]); }
        }
        *(f32x4*)&outk[off] = ka;
        *(f32x4*)&outk[off + 4] = kb;
        *(f32x4*)&outv[off] = va;
        *(f32x4*)&outv[off + 4] = vb;
      }
      u16x8 kv, vv;
#pragma unroll
      for (int u = 0; u < 4; ++u) {
        kv[u] = f2bf(ka[u]); kv[u + 4] = f2bf(kb[u]);
        vv[u] = f2bf(va[u]); vv[u + 4] = f2bf(vb[u]);
      }
      *(u32x4*)&kls[r][c8 * 4] = __builtin_bit_cast(u32x4, kv);
      *(u32x4*)&vls[r][c8 * 4] = __builtin_bit_cast(u32x4, vv);
    }
    __syncthreads();
    if (r0 >= nl) continue;

    float s[4] = {0.f,0.f,0.f,0.f};
#pragma unroll
    for (int dblk = 0; dblk < 4; ++dblk) {
      u32x4 qv[4];
#pragma unroll
      for (int g = 0; g < 4; ++g)
        qv[g] = *(const u32x4*)&qls[t][dblk * 16 + g * 4];
      float qf[32];
#pragma unroll
      for (int g = 0; g < 4; ++g)
#pragma unroll
        for (int u = 0; u < 4; ++u)
          unpk(qv[g][u], qf[g * 8 + 2 * u], qf[g * 8 + 2 * u + 1]);
#pragma unroll
      for (int jj = 0; jj < 4; ++jj) {
        const int j = js + jj * 16;
        u32x4 kv4[4];
#pragma unroll
        for (int g = 0; g < 4; ++g)
          kv4[g] = *(const u32x4*)&kls[j][dblk * 16 + g * 4];
        float a_ = s[jj];
#pragma unroll
        for (int g = 0; g < 4; ++g)
#pragma unroll
          for (int u = 0; u < 4; ++u) {
            float lo, hi; unpk(kv4[g][u], lo, hi);
            a_ += qf[g * 8 + 2 * u] * lo;
            a_ += qf[g * 8 + 2 * u + 1] * hi;
          }
        s[jj] = a_;
      }
    }

    float mt = -1e30f;
    bool val[4];
#pragma unroll
    for (int jj = 0; jj < 4; ++jj) {
      int jg = r0 + js + jj * 16;
      val[jj] = (jg <= qpos);
      if (!val[jj]) s[jj] = -1e30f;
      mt = fmaxf(mt, s[jj]);
    }
#pragma unroll
    for (int w = 1; w < 16; w <<= 1)
      mt = fmaxf(mt, __shfl_xor(mt, w));
    float mn = fmaxf(m_run, mt);
    float crr = __expf(m_run - mn);
    float p[4], ps = 0.f;
#pragma unroll
    for (int jj = 0; jj < 4; ++jj) {
      p[jj] = val[jj] ? __expf(s[jj] - mn) : 0.f;
      ps += p[jj];
    }
#pragma unroll
    for (int w = 1; w < 16; w <<= 1)
      ps += __shfl_xor(ps, w);
    l_run = l_run * crr + ps;
    m_run = mn;
#pragma unroll
    for (int jj = 0; jj < 4; ++jj)
      pls[t][js + jj * 16] = p[jj];
#pragma unroll
    for (int e = 0; e < 8; ++e) O[e] *= crr;
    __syncthreads();

    const int jmax = (nl - r0 < 64) ? (nl - r0) : 64;
#pragma unroll 2
    for (int j = 0; j < jmax; ++j) {
      float pv = pls[t][j];
      u32x4 vw = *(const u32x4*)&vls[j][js * 4];
#pragma unroll
      for (int g = 0; g < 4; ++g) {
        float lo, hi; unpk(vw[g], lo, hi);
        O[2 * g]     += pv * lo;
        O[2 * g + 1] += pv * hi;
      }
    }
  }

  float* sb = part + (size_t)(bh * NCH + chunk) * SLOT;
  u16* ob = (u16*)sb;
  u16x8 ov;
#pragma unroll
  for (int e = 0; e < 8; ++e) ov[e] = f2bf(O[e]);
  *(u16x8*)&ob[t * HD + js * 8] = ov;
  if (js == 0) { sb[1024 + t] = m_run; sb[1040 + t] = l_run; }
}

// ---------------------------------------------------------------------------
__global__ __launch_bounds__(128) void w11_comb(const float* __restrict__ part,
                                                float* __restrict__ attn)
{
  const int row = blockIdx.x;
  const int d = threadIdx.x;
  const int bh = row >> 4, t = row & 15;
  const float* pb = part + (size_t)bh * NCH * SLOT;
  float M = -1e30f;
#pragma unroll
  for (int c = 0; c < NCH; ++c) M = fmaxf(M, pb[c * SLOT + 1024 + t]);
  float L = 0.f, acc = 0.f;
#pragma unroll
  for (int c = 0; c < NCH; ++c) {
    float w = __expf(pb[c * SLOT + 1024 + t] - M);
    L   += w * pb[c * SLOT + 1040 + t];
    acc += w * bf2f(((const u16*)(pb + c * SLOT))[t * HD + d]);
  }
  const int b = bh >> 4, h = bh & 15;
  attn[(size_t)(b * Tt + t) * Cc + h * HD + d] = acc / L;
}

// ---------------------------------------------------------------------------
extern "C" void kernel_launch(void* const* d_in, const int* in_sizes, int n_in,
                              void* d_out, int out_size, void* d_ws, size_t ws_size,
                              hipStream_t stream)
{
  const void* x    = d_in[0];
  const void* kin  = d_in[1];
  const void* vin  = d_in[2];
  const void* wqkv = d_in[3];
  const void* wout = d_in[4];
  const void* ct   = d_in[5];
  const void* st   = d_in[6];
  const int*  clp  = (const int*)d_in[7];

  // outputs are f32: (out[262144], k_buf[67108864], v_buf[67108864])
  float* out_f = (float*)d_out;
  float* outk  = out_f + (size_t)Bb * Tt * Cc;
  float* outv  = outk + NKV;
  float* ws = (float*)d_ws;

  if (ws_size < WS_TOTAL * sizeof(float)) return;

  int* flags = (int*)(ws + WS_FLAG);
  u16* qbf   = (u16*)(ws + WS_QBF);

  w11_det<<<1, 64, 0, stream>>>((const u32*)x, (const u32*)kin, (const u32*)vin,
                                (const u32*)wqkv, (const u32*)wout,
                                (const u32*)ct, (const u32*)st, flags);
  // GEMM1 (MFMA bf16): x @ W_qkv -> qkv f32 in ws
  w11_mm<<<dim3(N3 / 64, 2), 256, 0, stream>>>(x, wqkv, N3, ws + WS_QKV,
                                               flags, 0, 3);
  w11_rot<<<128, 256, 0, stream>>>(ws + WS_QKV, ct, st, clp, qbf, outk, outv, flags);
  // fused copy + attention partials (partials reuse the now-dead qkv region)
  w11_attc<<<dim3(NCH, 128), 256, 0, stream>>>(kin, vin, qbf, clp,
                                               outk, outv, ws + WS_PART, flags);
  w11_comb<<<2048, 128, 0, stream>>>(ws + WS_PART, ws + WS_ATTN);
  // GEMM2 (MFMA bf16): attn @ W_out -> out f32 (direct, deterministic)
  w11_mm<<<dim3(Cc / 64, 2), 256, 0, stream>>>(ws + WS_ATTN, wout, Cc, out_f,
                                               flags, -1, 4);
}

// Round 12
// 303.640 us; speedup vs baseline: 3.6790x; 1.4569x over previous
//
#include <hip/hip_runtime.h>

typedef unsigned short u16;
typedef unsigned int   u32;
typedef u16  u16x4 __attribute__((ext_vector_type(4)));
typedef u16  u16x8 __attribute__((ext_vector_type(8)));
typedef u32  u32x4 __attribute__((ext_vector_type(4)));
typedef short s16x8 __attribute__((ext_vector_type(8)));
typedef float f32x2 __attribute__((ext_vector_type(2)));
typedef float f32x4 __attribute__((ext_vector_type(4)));

#define DEVFN static __device__ __forceinline__

DEVFN float bf2f(u16 v) { u32 t = (u32)v << 16; return __builtin_bit_cast(float, t); }
DEVFN u16 f2bf(float f) {
  u32 u = __builtin_bit_cast(u32, f);
  return (u16)((u + 0x7fffu + ((u >> 16) & 1u)) >> 16);
}
DEVFN void unpk(u32 w, float& lo, float& hi) {
  lo = __builtin_bit_cast(float, w << 16);
  hi = __builtin_bit_cast(float, w & 0xffff0000u);
}

constexpr int Bb = 8, Tt = 16, Cc = 2048, Hh = 16, HD = 128, ML = 4096;
constexpr int N3 = 3 * Cc;
constexpr float SCALE = 0.08838834764831845f;
constexpr size_t NKV = (size_t)Bb * Hh * ML * HD;   // 67108864
constexpr int NCH = 6;                              // attention K-split chunks

// ws layout (f32 units) — 4.72 MB guaranteed.
// [16, 786448): qkv f32 (mm1..rot), then attention O-partials (u16), exact fit:
//   768 slots x 1024 f32 = 786432.   m/l partials live in the dead out_f region.
constexpr size_t WS_FLAG = 0;
constexpr size_t WS_QKV  = 16;
constexpr size_t WS_PART = 16;
constexpr size_t WS_QBF  = 786448;   // 131072 f32 (u16 q, scaled+roped)
constexpr size_t WS_ATTN = 917520;   // 262144 f32
constexpr size_t WS_TOTAL = 1179664;

DEVFN int san_cl(int raw) {
  if (raw >= 0 && raw <= ML - Tt) return raw;
  float f = __builtin_bit_cast(float, raw);
  int v = (int)f;
  if (v >= 0 && v <= ML - Tt) return v;
  return 0;
}

// ---------------------------------------------------------------------------
DEVFN int w12_probe1(const u32* p, long long base, long long stride, int lane) {
  u32 w = p[base + (long long)lane * stride];
  u32 e = (w >> 7) & 0xffu;
  unsigned long long b = __ballot(e >= 100u && e <= 140u);
  return (__popcll(b) >= 32) ? 0 : 1;   // 0 = bf16, 1 = f32
}

__global__ void w12_det(const u32* x, const u32* kb, const u32* vb,
                        const u32* wq, const u32* wo, const u32* ct,
                        const u32* st, int* flags)
{
  int lane = threadIdx.x;  // 64
  int f0 = w12_probe1(x,  40000,    997,    lane);
  int f1 = w12_probe1(kb, 10000000, 300001, lane);
  int f2 = w12_probe1(vb, 10000000, 300001, lane);
  int f3 = w12_probe1(wq, 2000000,  33331,  lane);
  int f4 = w12_probe1(wo, 700000,   17177,  lane);
  int f5 = w12_probe1(ct, 40000,    997,    lane);
  int f6 = w12_probe1(st, 40000,    997,    lane);
  if (lane == 0) {
    flags[0] = f0; flags[1] = f1; flags[2] = f2; flags[3] = f3;
    flags[4] = f4; flags[5] = f5; flags[6] = f6; flags[7] = 0;
  }
}

// ---------------------------------------------------------------------------
// MFMA bf16 GEMM core: tile 64M x 64N, K-step 64, K range [kbeg, kbeg+512).
// mfma_f32_16x16x32_bf16 layout (verified):
//   A-frag: lane l holds A[l&15][(l>>4)*8 + e]
//   B-frag: lane l holds B[(l>>4)*8 + e][l&15]
//   D:      row = (l>>4)*4 + j, col = l&15
// ---------------------------------------------------------------------------
DEVFN void w12_mm_core(const void* __restrict__ A, const void* __restrict__ W,
                       int ldn, int fa, int fw, int kbeg, int m0, int n0,
                       u16 (&As)[64][72], u16 (&Bs)[8][66][8], f32x4 (&acc)[4])
{
  const int tid = threadIdx.x;
  const int l = tid & 63, wv = tid >> 6;
  for (int k0 = kbeg; k0 < kbeg + 512; k0 += 64) {
    __syncthreads();
    // stage A 64x64 -> As (bf16)
#pragma unroll
    for (int it = 0; it < 2; ++it) {
      int idx = it * 256 + tid, row = idx >> 3, kc = (idx & 7) * 8;
      if (fa) {
        const float* Af = (const float*)A + (size_t)(m0 + row) * Cc + k0 + kc;
        f32x4 a0 = *(const f32x4*)Af;
        f32x4 a1 = *(const f32x4*)(Af + 4);
        u16x8 av;
#pragma unroll
        for (int u = 0; u < 4; ++u) { av[u] = f2bf(a0[u]); av[u + 4] = f2bf(a1[u]); }
        *(u16x8*)&As[row][kc] = av;
      } else {
        u16x8 av = *(const u16x8*)((const u16*)A + (size_t)(m0 + row) * Cc + k0 + kc);
        *(u16x8*)&As[row][kc] = av;
      }
    }
    // stage B 64x64 -> Bs swizzled [kk>>3][n][kk&7]
#pragma unroll
    for (int i = 0; i < 4; ++i) {
      int kk = i * 16 + (tid >> 4);
      int nn = (tid & 15) * 4;
      if (fw) {
        f32x4 bv = *(const f32x4*)((const float*)W + (size_t)(k0 + kk) * ldn + n0 + nn);
#pragma unroll
        for (int u = 0; u < 4; ++u) Bs[kk >> 3][nn + u][kk & 7] = f2bf(bv[u]);
      } else {
        u16x4 bv = *(const u16x4*)((const u16*)W + (size_t)(k0 + kk) * ldn + n0 + nn);
#pragma unroll
        for (int u = 0; u < 4; ++u) Bs[kk >> 3][nn + u][kk & 7] = bv[u];
      }
    }
    __syncthreads();
    // compute: 2 k-substeps x (1 A-frag + 4 B-frags -> 4 MFMA)
#pragma unroll
    for (int ks = 0; ks < 2; ++ks) {
      s16x8 a = __builtin_bit_cast(s16x8,
          *(const u16x8*)&As[wv * 16 + (l & 15)][ks * 32 + (l >> 4) * 8]);
#pragma unroll
      for (int nf = 0; nf < 4; ++nf) {
        s16x8 b = __builtin_bit_cast(s16x8,
            *(const u16x8*)&Bs[ks * 4 + (l >> 4)][nf * 16 + (l & 15)][0]);
        acc[nf] = __builtin_amdgcn_mfma_f32_16x16x32_bf16(a, b, acc[nf], 0, 0, 0);
      }
    }
  }
}

// GEMM1: k-split x4, partials -> park buffer. grid (ldn/64, 2, 4).
__global__ __launch_bounds__(256) void w12_mmp(const void* __restrict__ A,
    const void* __restrict__ W, int ldn, float* __restrict__ part,
    const int* __restrict__ flags)
{
  __shared__ u16 As[64][72];
  __shared__ u16 Bs[8][66][8];
  const int n0 = blockIdx.x * 64, m0 = blockIdx.y * 64, s = blockIdx.z;
  f32x4 acc[4] = {{0.f,0.f,0.f,0.f},{0.f,0.f,0.f,0.f},
                  {0.f,0.f,0.f,0.f},{0.f,0.f,0.f,0.f}};
  w12_mm_core(A, W, ldn, flags[0], flags[3], s * 512, m0, n0, As, Bs, acc);
  const int l = threadIdx.x & 63, wv = threadIdx.x >> 6;
  const int row = m0 + wv * 16 + (l >> 4) * 4;
  const int colb = n0 + (l & 15);
  float* pb = part + (size_t)s * 128 * ldn;
#pragma unroll
  for (int nf = 0; nf < 4; ++nf)
#pragma unroll
    for (int j = 0; j < 4; ++j)
      pb[(size_t)(row + j) * ldn + colb + nf * 16] = acc[nf][j];
}

// reduce 4 partial slices -> qkv. grid 768 x 256.
__global__ __launch_bounds__(256) void w12_red1(const float* __restrict__ part,
                                                float* __restrict__ qkv)
{
  size_t e4 = (size_t)blockIdx.x * 256 + threadIdx.x;
  f32x4 acc = {0.f, 0.f, 0.f, 0.f};
#pragma unroll
  for (int s = 0; s < 4; ++s) {
    f32x4 v = *(const f32x4*)&part[(size_t)s * 786432 + e4 * 4];
    acc[0] += v[0]; acc[1] += v[1]; acc[2] += v[2]; acc[3] += v[3];
  }
  *(f32x4*)&qkv[e4 * 4] = acc;
}

// GEMM2: k-split x4 + atomic accumulate into pre-zeroed out. grid (32, 2, 4).
__global__ __launch_bounds__(256) void w12_mma(const float* __restrict__ A,
    const void* __restrict__ W, int ldn, float* __restrict__ outp,
    const int* __restrict__ flags)
{
  __shared__ u16 As[64][72];
  __shared__ u16 Bs[8][66][8];
  const int n0 = blockIdx.x * 64, m0 = blockIdx.y * 64, s = blockIdx.z;
  f32x4 acc[4] = {{0.f,0.f,0.f,0.f},{0.f,0.f,0.f,0.f},
                  {0.f,0.f,0.f,0.f},{0.f,0.f,0.f,0.f}};
  w12_mm_core(A, W, ldn, 1, flags[4], s * 512, m0, n0, As, Bs, acc);
  const int l = threadIdx.x & 63, wv = threadIdx.x >> 6;
  const int row = m0 + wv * 16 + (l >> 4) * 4;
  const int colb = n0 + (l & 15);
#pragma unroll
  for (int nf = 0; nf < 4; ++nf)
#pragma unroll
    for (int j = 0; j < 4; ++j)
      atomicAdd(&outp[(size_t)(row + j) * ldn + colb + nf * 16], acc[nf][j]);
}

__global__ __launch_bounds__(256) void w12_zero(float* __restrict__ outp) {
  size_t i = ((size_t)blockIdx.x * 256 + threadIdx.x) * 4;
  f32x4 z = {0.f, 0.f, 0.f, 0.f};
  *(f32x4*)&outp[i] = z;
}

// ---------------------------------------------------------------------------
// RoPE q,k; scale q; q -> qbf (bf16); fresh k,v -> F32 output cache.
// grid (128, 2), 256 thr.
// ---------------------------------------------------------------------------
__global__ __launch_bounds__(256) void w12_rot(const float* __restrict__ qkv,
    const void* __restrict__ ct, const void* __restrict__ st,
    const int* __restrict__ clp, u16* __restrict__ qbf,
    float* __restrict__ outk, float* __restrict__ outv,
    const int* __restrict__ flags)
{
  const int m = blockIdx.x, b = m >> 4, t = m & 15;
  const int half = blockIdx.y;
  const int cl = san_cl(*clp), pos = cl + t;
  const int fc = flags[5], fs = flags[6];
  const float* qr = qkv + (size_t)m * N3;
  for (int i0 = half * 512 + threadIdx.x; i0 < half * 512 + 512; i0 += 256) {
    int h = i0 >> 6, i = i0 & 63;
    float cs = fc ? ((const float*)ct)[pos * 64 + i] : bf2f(((const u16*)ct)[pos * 64 + i]);
    float sn = fs ? ((const float*)st)[pos * 64 + i] : bf2f(((const u16*)st)[pos * 64 + i]);
    int col = h * HD + 2 * i;
    float q0 = qr[col], q1 = qr[col + 1];
    qbf[(size_t)m * Cc + col]     = f2bf((q0 * cs - q1 * sn) * SCALE);
    qbf[(size_t)m * Cc + col + 1] = f2bf((q1 * cs + q0 * sn) * SCALE);
    float k0 = qr[2048 + col], k1 = qr[2048 + col + 1];
    size_t ko = ((size_t)(b * Hh + h) * ML + pos) * HD + 2 * i;
    outk[ko]     = k0 * cs - k1 * sn;
    outk[ko + 1] = k1 * cs + k0 * sn;
    outv[ko]     = qr[4096 + col];
    outv[ko + 1] = qr[4096 + col + 1];
  }
}

// ---------------------------------------------------------------------------
// FUSED cache-copy + flash-attention partials. grid (NCH=6, 128 bh), 256 thr.
// Chunk c handles subtiles c, c+6, ... (64 rows each; 64 subtiles total).
// O-partials (bf16) -> ws slot; m/l partials -> mlb (dead out_f region).
// ---------------------------------------------------------------------------
__global__ __launch_bounds__(256) void w12_attc(
    const void* __restrict__ kin, const void* __restrict__ vin,
    const u16* __restrict__ qbf, const int* __restrict__ clp,
    float* __restrict__ outk, float* __restrict__ outv,
    float* __restrict__ part, float* __restrict__ mlb,
    const int* __restrict__ flags)
{
  __shared__ u32 kls[64][68];
  __shared__ u32 vls[64][68];
  __shared__ u32 qls[16][68];
  __shared__ float pls[16][68];

  const int tid = threadIdx.x;
  const int chunk = blockIdx.x;   // 0..5
  const int bh = blockIdx.y;      // 0..127
  const int cl = san_cl(*clp), nl = cl + Tt;
  const int fk = flags[1], fv = flags[2];
  const size_t base = (size_t)bh * ML * HD;
  const int b = bh >> 4, h = bh & 15;

  { // stage q tile (16 x 128 bf16)
    const u16* qsrc = qbf + (size_t)b * Tt * Cc + h * HD;
    int r = tid >> 4, c8 = tid & 15;
    u16x8 qv = *(const u16x8*)&qsrc[(size_t)r * Cc + c8 * 8];
    *(u32x4*)&qls[r][c8 * 4] = __builtin_bit_cast(u32x4, qv);
  }

  const int t = tid >> 4;
  const int js = tid & 15;
  const int qpos = cl + t;
  float m_run = -1e30f, l_run = 0.f;
  float O[8] = {0.f,0.f,0.f,0.f,0.f,0.f,0.f,0.f};

  for (int st8 = chunk; st8 < 64; st8 += NCH) {
    const int r0 = st8 * 64;
    __syncthreads();
#pragma unroll
    for (int ii = 0; ii < 4; ++ii) {
      int idx = ii * 256 + tid, r = idx >> 4, c8 = idx & 15;
      int jg = r0 + r;
      size_t off = base + (size_t)jg * HD + c8 * 8;
      bool fresh = (jg >= cl) && (jg < nl);
      f32x4 ka, kb, va, vb;
      if (fresh) {
        ka = *(const f32x4*)&outk[off];
        kb = *(const f32x4*)&outk[off + 4];
        va = *(const f32x4*)&outv[off];
        vb = *(const f32x4*)&outv[off + 4];
      } else {
        if (fk) {
          ka = *(const f32x4*)((const float*)kin + off);
          kb = *(const f32x4*)((const float*)kin + off + 4);
        } else {
          u16x8 kv8 = *(const u16x8*)((const u16*)kin + off);
          for (int u = 0; u < 4; ++u) { ka[u] = bf2f(kv8[u]); kb[u] = bf2f(kv8[u + 4]); }
        }
        if (fv) {
          va = *(const f32x4*)((const float*)vin + off);
          vb = *(const f32x4*)((const float*)vin + off + 4);
        } else {
          u16x8 vv8 = *(const u16x8*)((const u16*)vin + off);
          for (int u = 0; u < 4; ++u) { va[u] = bf2f(vv8[u]); vb[u] = bf2f(vv8[u + 4]); }
        }
        *(f32x4*)&outk[off] = ka;
        *(f32x4*)&outk[off + 4] = kb;
        *(f32x4*)&outv[off] = va;
        *(f32x4*)&outv[off + 4] = vb;
      }
      u16x8 kv, vv;
#pragma unroll
      for (int u = 0; u < 4; ++u) {
        kv[u] = f2bf(ka[u]); kv[u + 4] = f2bf(kb[u]);
        vv[u] = f2bf(va[u]); vv[u + 4] = f2bf(vb[u]);
      }
      *(u32x4*)&kls[r][c8 * 4] = __builtin_bit_cast(u32x4, kv);
      *(u32x4*)&vls[r][c8 * 4] = __builtin_bit_cast(u32x4, vv);
    }
    __syncthreads();
    if (r0 >= nl) continue;

    float s[4] = {0.f,0.f,0.f,0.f};
#pragma unroll
    for (int dblk = 0; dblk < 4; ++dblk) {
      u32x4 qv[4];
#pragma unroll
      for (int g = 0; g < 4; ++g)
        qv[g] = *(const u32x4*)&qls[t][dblk * 16 + g * 4];
      float qf[32];
#pragma unroll
      for (int g = 0; g < 4; ++g)
#pragma unroll
        for (int u = 0; u < 4; ++u)
          unpk(qv[g][u], qf[g * 8 + 2 * u], qf[g * 8 + 2 * u + 1]);
#pragma unroll
      for (int jj = 0; jj < 4; ++jj) {
        const int j = js + jj * 16;
        u32x4 kv4[4];
#pragma unroll
        for (int g = 0; g < 4; ++g)
          kv4[g] = *(const u32x4*)&kls[j][dblk * 16 + g * 4];
        float a_ = s[jj];
#pragma unroll
        for (int g = 0; g < 4; ++g)
#pragma unroll
          for (int u = 0; u < 4; ++u) {
            float lo, hi; unpk(kv4[g][u], lo, hi);
            a_ += qf[g * 8 + 2 * u] * lo;
            a_ += qf[g * 8 + 2 * u + 1] * hi;
          }
        s[jj] = a_;
      }
    }

    float mt = -1e30f;
    bool val[4];
#pragma unroll
    for (int jj = 0; jj < 4; ++jj) {
      int jg = r0 + js + jj * 16;
      val[jj] = (jg <= qpos);
      if (!val[jj]) s[jj] = -1e30f;
      mt = fmaxf(mt, s[jj]);
    }
#pragma unroll
    for (int w = 1; w < 16; w <<= 1)
      mt = fmaxf(mt, __shfl_xor(mt, w));
    float mn = fmaxf(m_run, mt);
    float crr = __expf(m_run - mn);
    float p[4], ps = 0.f;
#pragma unroll
    for (int jj = 0; jj < 4; ++jj) {
      p[jj] = val[jj] ? __expf(s[jj] - mn) : 0.f;
      ps += p[jj];
    }
#pragma unroll
    for (int w = 1; w < 16; w <<= 1)
      ps += __shfl_xor(ps, w);
    l_run = l_run * crr + ps;
    m_run = mn;
#pragma unroll
    for (int jj = 0; jj < 4; ++jj)
      pls[t][js + jj * 16] = p[jj];
#pragma unroll
    for (int e = 0; e < 8; ++e) O[e] *= crr;
    __syncthreads();

    const int jmax = (nl - r0 < 64) ? (nl - r0) : 64;
#pragma unroll 2
    for (int j = 0; j < jmax; ++j) {
      float pv = pls[t][j];
      u32x4 vw = *(const u32x4*)&vls[j][js * 4];
#pragma unroll
      for (int g = 0; g < 4; ++g) {
        float lo, hi; unpk(vw[g], lo, hi);
        O[2 * g]     += pv * lo;
        O[2 * g + 1] += pv * hi;
      }
    }
  }

  // partial O (bf16) -> ws slot; m,l -> mlb slot
  const int slot = bh * NCH + chunk;
  u16* ob = (u16*)(part + (size_t)slot * 1024);
  u16x8 ov;
#pragma unroll
  for (int e = 0; e < 8; ++e) ov[e] = f2bf(O[e]);
  *(u16x8*)&ob[t * HD + js * 8] = ov;
  if (js == 0) { mlb[slot * 32 + t] = m_run; mlb[slot * 32 + 16 + t] = l_run; }
}

// ---------------------------------------------------------------------------
// Combine NCH chunk partials -> attn (f32). grid 2048 (bh*16+t), 128 thr (d).
// ---------------------------------------------------------------------------
__global__ __launch_bounds__(128) void w12_comb(const float* __restrict__ part,
    const float* __restrict__ mlb, float* __restrict__ attn)
{
  const int row = blockIdx.x;
  const int d = threadIdx.x;
  const int bh = row >> 4, t = row & 15;
  float M = -1e30f;
#pragma unroll
  for (int c = 0; c < NCH; ++c) M = fmaxf(M, mlb[(bh * NCH + c) * 32 + t]);
  float L = 0.f, acc = 0.f;
#pragma unroll
  for (int c = 0; c < NCH; ++c) {
    const int slot = bh * NCH + c;
    float w = __expf(mlb[slot * 32 + t] - M);
    L   += w * mlb[slot * 32 + 16 + t];
    acc += w * bf2f(((const u16*)(part + (size_t)slot * 1024))[t * HD + d]);
  }
  const int b = bh >> 4, h = bh & 15;
  attn[(size_t)(b * Tt + t) * Cc + h * HD + d] = acc / L;
}

// ---------------------------------------------------------------------------
extern "C" void kernel_launch(void* const* d_in, const int* in_sizes, int n_in,
                              void* d_out, int out_size, void* d_ws, size_t ws_size,
                              hipStream_t stream)
{
  const void* x    = d_in[0];
  const void* kin  = d_in[1];
  const void* vin  = d_in[2];
  const void* wqkv = d_in[3];
  const void* wout = d_in[4];
  const void* ct   = d_in[5];
  const void* st   = d_in[6];
  const int*  clp  = (const int*)d_in[7];

  // outputs are f32: (out[262144], k_buf[67108864], v_buf[67108864])
  float* out_f = (float*)d_out;
  float* outk  = out_f + (size_t)Bb * Tt * Cc;
  float* outv  = outk + NKV;
  float* ws = (float*)d_ws;

  if (ws_size < WS_TOTAL * sizeof(float)) return;

  int* flags = (int*)(ws + WS_FLAG);
  u16* qbf   = (u16*)(ws + WS_QBF);

  w12_det<<<1, 64, 0, stream>>>((const u32*)x, (const u32*)kin, (const u32*)vin,
                                (const u32*)wqkv, (const u32*)wout,
                                (const u32*)ct, (const u32*)st, flags);
  // GEMM1 (MFMA, K-split x4): partials parked in dead outv, then reduced
  w12_mmp<<<dim3(N3 / 64, 2, 4), 256, 0, stream>>>(x, wqkv, N3, outv, flags);
  w12_red1<<<768, 256, 0, stream>>>(outv, ws + WS_QKV);
  w12_rot<<<dim3(128, 2), 256, 0, stream>>>(ws + WS_QKV, ct, st, clp, qbf,
                                            outk, outv, flags);
  // fused copy + attention partials (O -> dead qkv region, m/l -> dead out_f)
  w12_attc<<<dim3(NCH, 128), 256, 0, stream>>>(kin, vin, qbf, clp, outk, outv,
                                               ws + WS_PART, out_f, flags);
  w12_comb<<<2048, 128, 0, stream>>>(ws + WS_PART, out_f, ws + WS_ATTN);
  // GEMM2 (MFMA, K-split x4): atomic accumulate into pre-zeroed out
  w12_zero<<<256, 256, 0, stream>>>(out_f);
  w12_mma<<<dim3(Cc / 64, 2, 4), 256, 0, stream>>>(ws + WS_ATTN, wout, Cc,
                                                   out_f, flags);
}